// Round 10
// baseline (18631.470 us; speedup 1.0000x reference)
//
#include <hip/hip_runtime.h>

// Problem: x (B=4, C=256, D=32, H=64, W=64) fp32.
// 1) reflect-pad(2) + per-(b,c) mean  == weighted sum over original x
// 2) LSTMCell scan over C=256 channels (B=4, hidden=32, input=1)
// 3) gate[b,c] = sigmoid(h_c . gate_w + gate_b);  out = x * gate[b,c]
//
// R10: producer-consumer PIPELINE in one plain kernel. Blocks take a global
// ticket; ticket->work map interleaves mean-quarters and scale-quarters with
// a W_HEAD head start, so scale(c) re-reads x[c] within ~130MB of traffic
// after mean(c) -> L3 hits instead of HBM re-fetch. LSTM = ticket 0 (4 waves,
// one per batch), consuming mean-quads as they land, publishing gates.
// Deadlock-free: means never wait; LSTM waits only on means; scales wait only
// on LSTM (resident from ticket 0). Deterministic: fixed-order partial sums.

#define MEAN_DEN (1.0f / 166464.0f)   // 36*68*68
#define W_HEAD 512                    // mean-quarter head start (64 MB)
#define NMEAN 4096                    // 1024 channels x 4 quarters
#define BND2 (1 + W_HEAD + 2 * (NMEAN - W_HEAD))   // 7681
#define NTICK (BND2 + W_HEAD)                      // 8193 blocks

typedef unsigned int uint;
typedef float f32x4 __attribute__((ext_vector_type(4)));

__device__ __forceinline__ float sigf(float x) {
    return 1.0f / (1.0f + __expf(-x));
}
__device__ __forceinline__ float tanh_fast(float x) {
    return fmaf(2.0f, sigf(2.0f * x), -1.0f);   // tanh(x) = 2*sigmoid(2x) - 1
}
__device__ __forceinline__ uint ld_acq(const uint* p) {
    return __hip_atomic_load(p, __ATOMIC_ACQUIRE, __HIP_MEMORY_SCOPE_AGENT);
}
__device__ __forceinline__ void st_rel(uint* p, uint v) {
    __hip_atomic_store(p, v, __ATOMIC_RELEASE, __HIP_MEMORY_SCOPE_AGENT);
}
__device__ __forceinline__ void add_rel(uint* p) {
    __hip_atomic_fetch_add(p, 1u, __ATOMIC_RELEASE, __HIP_MEMORY_SCOPE_AGENT);
}

#define RL(v, k) __builtin_bit_cast(float, \
    __builtin_amdgcn_readlane(__builtin_bit_cast(int, (v)), (k)))
#define DW(k) const float w0_##k = W_hh[r0 * 32 + (k)]; \
              const float w1_##k = W_hh[r1 * 32 + (k)];
#define GK(k, A0, A1) { const float hk = RL(h, k); \
                A0 = fmaf(hk, w0_##k, A0); A1 = fmaf(hk, w1_##k, A1); }

// ws layout (4B units): [0] ticket | [64..1088) qcnt[c*4+b] | [2048..6144)
// part4[c*16+b*4+q] | [6400..7424) gates[b*256+c] | [7680..7684) gprog[b]
__global__ __launch_bounds__(256) void pipe_kernel(
    const float* __restrict__ x,
    const float* __restrict__ W_ih, const float* __restrict__ W_hh,
    const float* __restrict__ b_ih, const float* __restrict__ b_hh,
    const float* __restrict__ gate_w, const float* __restrict__ gate_b,
    float* __restrict__ out, float* __restrict__ ws)
{
    __shared__ float red[256];
    __shared__ uint s_t;
    uint*  ctrl  = (uint*)ws;
    uint*  qcnt  = ctrl + 64;
    float* part4 = ws + 2048;
    float* gates = ws + 6400;
    uint*  gprog = ctrl + 7680;

    const int tid = threadIdx.x;
    if (tid == 0) s_t = atomicAdd(ctrl, 1u);
    __syncthreads();
    const uint T = s_t;

    if (T == 0u) {
        // ---------- LSTM role: 4 waves, wave b = batch b ----------
        const int b = tid >> 6, l = tid & 63;
        const int r0 = l, r1 = l + 64;
        const float wih0 = W_ih[r0], wih1 = W_ih[r1];
        const float bias0 = b_ih[r0] + b_hh[r0];
        const float bias1 = b_ih[r1] + b_hh[r1];
        DW(0)  DW(1)  DW(2)  DW(3)  DW(4)  DW(5)  DW(6)  DW(7)
        DW(8)  DW(9)  DW(10) DW(11) DW(12) DW(13) DW(14) DW(15)
        DW(16) DW(17) DW(18) DW(19) DW(20) DW(21) DW(22) DW(23)
        DW(24) DW(25) DW(26) DW(27) DW(28) DW(29) DW(30) DW(31)
        const float gwl = gate_w[l & 31];
        const float gb = gate_b[0];
        float h = 0.0f, cst = 0.0f;

        for (int c = 0; c < 256; c++) {
            while (ld_acq(&qcnt[c * 4 + b]) < 4u) __builtin_amdgcn_s_sleep(1);
            const float* pp = &part4[c * 16 + b * 4];
            const float inp = ((pp[0] + pp[1]) + (pp[2] + pp[3])) * MEAN_DEN;
            float a0 = fmaf(inp, wih0, bias0), b0 = 0.f, c0 = 0.f, d0 = 0.f;
            float a1 = fmaf(inp, wih1, bias1), b1 = 0.f, c1 = 0.f, d1 = 0.f;
            GK(0,a0,a1)  GK(1,b0,b1)  GK(2,c0,c1)  GK(3,d0,d1)
            GK(4,a0,a1)  GK(5,b0,b1)  GK(6,c0,c1)  GK(7,d0,d1)
            GK(8,a0,a1)  GK(9,b0,b1)  GK(10,c0,c1) GK(11,d0,d1)
            GK(12,a0,a1) GK(13,b0,b1) GK(14,c0,c1) GK(15,d0,d1)
            GK(16,a0,a1) GK(17,b0,b1) GK(18,c0,c1) GK(19,d0,d1)
            GK(20,a0,a1) GK(21,b0,b1) GK(22,c0,c1) GK(23,d0,d1)
            GK(24,a0,a1) GK(25,b0,b1) GK(26,c0,c1) GK(27,d0,d1)
            GK(28,a0,a1) GK(29,b0,b1) GK(30,c0,c1) GK(31,d0,d1)
            const float z0 = (a0 + b0) + (c0 + d0);
            const float z1 = (a1 + b1) + (c1 + d1);
            float zf, zo;
#if __has_builtin(__builtin_amdgcn_permlane32_swap)
            {
                auto ra = __builtin_amdgcn_permlane32_swap(
                    __builtin_bit_cast(uint, z0), __builtin_bit_cast(uint, z0), false, false);
                auto rb = __builtin_amdgcn_permlane32_swap(
                    __builtin_bit_cast(uint, z1), __builtin_bit_cast(uint, z1), false, false);
                zf = __builtin_bit_cast(float, ra[1]);
                zo = __builtin_bit_cast(float, rb[1]);
            }
#else
            zf = __shfl_xor(z0, 32);
            zo = __shfl_xor(z1, 32);
#endif
            // valid in lanes<32 only (upper lanes: finite-or-inf garbage, never read)
            cst = sigf(zf) * cst + sigf(z0) * tanh_fast(z1);
            h = sigf(zo) * tanh_fast(cst);
            // gate[b][c] = sigmoid(dot(h, gate_w) + gate_b), published immediately
            float p = h * gwl;
            p += __shfl_xor(p, 1);  p += __shfl_xor(p, 2);  p += __shfl_xor(p, 4);
            p += __shfl_xor(p, 8);  p += __shfl_xor(p, 16);
            if (l == 0) {
                gates[b * 256 + c] = sigf(p + gb);
                st_rel(&gprog[b], (uint)(c + 1));
            }
        }
        return;
    }

    // ---------- ticket -> work map ----------
    int mitem = -1, sitem = -1;
    if (T < 1u + W_HEAD) {
        mitem = (int)T - 1;
    } else if (T < (uint)BND2) {
        const uint rel = T - 1u - W_HEAD;
        if ((rel & 1u) == 0u) mitem = W_HEAD + (int)(rel >> 1);
        else                  sitem = (int)(rel >> 1);
    } else {
        sitem = (NMEAN - W_HEAD) + (int)(T - (uint)BND2);
    }
    // item -> (scan step c, batch b, quarter q); scan-order major
    if (mitem >= 0) {
        // ---------- mean quarter (128 KB) ----------
        const int c = mitem >> 4, b = (mitem >> 2) & 3, q = mitem & 3;
        const f32x4* __restrict__ p =
            (const f32x4*)x + (((size_t)(b * 256 + c)) << 15) + (q << 13);
        const int base = q << 13;          // f4 offset within channel
        float s0 = 0.f, s1 = 0.f, s2 = 0.f, s3 = 0.f;
#pragma unroll
        for (int g = 0; g < 4; g++) {
            f32x4 v[8];
#pragma unroll
            for (int u = 0; u < 8; u++) v[u] = p[g * 2048 + u * 256 + tid];
#pragma unroll
            for (int u = 0; u < 8; u++) {
                const int i = base + g * 2048 + u * 256 + tid;
                const int qq = i & 15, hh = (i >> 4) & 63, d = i >> 10;
                float t = (v[u].x + v[u].y) + (v[u].z + v[u].w);
                if (qq == 0 || qq == 15) t += v[u].y + v[u].z;   // W 1,2,61,62 x2
                const float wd = ((d == 1) | (d == 2) | (d == 29) | (d == 30)) ? 2.f : 1.f;
                const float wh = ((hh == 1) | (hh == 2) | (hh == 61) | (hh == 62)) ? 2.f : 1.f;
                const float w = wd * wh;
                if ((u & 3) == 0)      s0 = fmaf(w, t, s0);
                else if ((u & 3) == 1) s1 = fmaf(w, t, s1);
                else if ((u & 3) == 2) s2 = fmaf(w, t, s2);
                else                   s3 = fmaf(w, t, s3);
            }
        }
        red[tid] = (s0 + s1) + (s2 + s3);
        __syncthreads();
        for (int s = 128; s > 0; s >>= 1) {
            if (tid < s) red[tid] += red[tid + s];
            __syncthreads();
        }
        if (tid == 0) {
            part4[mitem] = red[0];          // plain store, then release-count
            add_rel(&qcnt[c * 4 + b]);
        }
        return;
    }

    // ---------- scale quarter (128 KB): out = x * gate ----------
    {
        const int c = sitem >> 4, b = (sitem >> 2) & 3, q = sitem & 3;
        const int bc = b * 256 + c;
        while (ld_acq(&gprog[b]) <= (uint)c) __builtin_amdgcn_s_sleep(8);
        const float g = gates[bc];
        const size_t off = (((size_t)bc) << 15) + (q << 13);
        const f32x4* __restrict__ xi = (const f32x4*)x + off;
        f32x4* __restrict__ oi = (f32x4*)out + off;
#pragma unroll
        for (int gr = 0; gr < 4; gr++) {
            f32x4 v[8];
#pragma unroll
            for (int u = 0; u < 8; u++) v[u] = xi[gr * 2048 + u * 256 + tid];
#pragma unroll
            for (int u = 0; u < 8; u++) {
                v[u] *= g;
                oi[gr * 2048 + u * 256 + tid] = v[u];
            }
        }
    }
}

extern "C" void kernel_launch(void* const* d_in, const int* in_sizes, int n_in,
                              void* d_out, int out_size, void* d_ws, size_t ws_size,
                              hipStream_t stream) {
    const float* x      = (const float*)d_in[0];
    const float* W_ih   = (const float*)d_in[1];   // (128,1)
    const float* W_hh   = (const float*)d_in[2];   // (128,32)
    const float* b_ih   = (const float*)d_in[3];   // (128,)
    const float* b_hh   = (const float*)d_in[4];   // (128,)
    const float* gate_w = (const float*)d_in[5];   // (1,32)
    const float* gate_b = (const float*)d_in[6];   // (1,)
    float* out = (float*)d_out;
    float* ws  = (float*)d_ws;                     // 32 KB control + buffers

    // reset ticket/counters/progress every call (capture-safe, deterministic)
    hipMemsetAsync(d_ws, 0, 32768, stream);
    pipe_kernel<<<NTICK, 256, 0, stream>>>(x, W_ih, W_hh, b_ih, b_hh,
                                           gate_w, gate_b, out, ws);
}

// Round 11
// 391.998 us; speedup vs baseline: 47.5296x; 47.5296x over previous
//
#include <hip/hip_runtime.h>

// Problem: x (B=4, C=256, D=32, H=64, W=64) fp32.
// 1) reflect-pad(2) + per-(b,c) mean  == weighted sum over original x
// 2) LSTMCell scan over C=256 channels (B=4, hidden=32, input=1)
// 3) gate[b,c] = sigmoid(h_c . gate_w + gate_b);  out = x * gate[b,c]
//
// R11: back to the R8 3-kernel structure, with the R9 measurement lessons:
//   - scale uses NORMAL stores (R9: 151us/rep @5.33TB/s, FETCH half-L3-absorbed;
//     NT stores bypass L3 and cost ~90us extra -> R8's 245us scale).
//   - mean ~85us cold (R9 back-solve), keep unroll-8 + if-chain accumulators.
//   - R10's ticket pipeline livelocked (spinning scale blocks starved means);
//     persistent-block rework not worth the risk vs ~15us of launch gaps.

#define MEAN_DEN (1.0f / 166464.0f)   // 36*68*68

typedef unsigned int uint;
typedef float f32x4 __attribute__((ext_vector_type(4)));
typedef float f32x2 __attribute__((ext_vector_type(2)));

__device__ __forceinline__ float sigf(float x) {
    return 1.0f / (1.0f + __expf(-x));
}
__device__ __forceinline__ float tanh_fast(float x) {
    return fmaf(2.0f, sigf(2.0f * x), -1.0f);   // tanh(x) = 2*sigmoid(2x) - 1
}

// ---------- Kernel 1: weighted half-channel partial sums ----------
// 2048 blocks (8/CU, 100% occupancy). Block bid: channel bid>>1, half bid&1
// (16384 f4 = 256KB contiguous). 8 independent loads in flight per thread.
__global__ __launch_bounds__(256) void mean_kernel(const float* __restrict__ x,
                                                   float* __restrict__ part) {
    const int bid = blockIdx.x;
    const int ch = bid >> 1, half = bid & 1;
    const f32x4* __restrict__ p = (const f32x4*)x + (size_t)ch * 32768 + half * 16384;
    const int base = half * 16384;
    const int tid = threadIdx.x;

    float s0 = 0.0f, s1 = 0.0f, s2 = 0.0f, s3 = 0.0f;
#pragma unroll
    for (int g = 0; g < 8; g++) {
        f32x4 v[8];
#pragma unroll
        for (int u = 0; u < 8; u++) v[u] = p[g * 2048 + u * 256 + tid];
#pragma unroll
        for (int u = 0; u < 8; u++) {
            const int i = base + g * 2048 + u * 256 + tid;
            const int q = i & 15;             // f4 index within W-row
            const int hh = (i >> 4) & 63;
            const int d = i >> 10;
            float t = (v[u].x + v[u].y) + (v[u].z + v[u].w);
            if (q == 0 || q == 15) t += v[u].y + v[u].z;   // W 1,2,61,62 doubled
            const float wd = ((d == 1) | (d == 2) | (d == 29) | (d == 30)) ? 2.0f : 1.0f;
            const float wh = ((hh == 1) | (hh == 2) | (hh == 61) | (hh == 62)) ? 2.0f : 1.0f;
            const float w = wd * wh;
            if ((u & 3) == 0)      s0 = fmaf(w, t, s0);
            else if ((u & 3) == 1) s1 = fmaf(w, t, s1);
            else if ((u & 3) == 2) s2 = fmaf(w, t, s2);
            else                   s3 = fmaf(w, t, s3);
        }
    }
    float sum = (s0 + s1) + (s2 + s3);

    __shared__ float red[256];
    red[tid] = sum;
    __syncthreads();
    for (int s = 128; s > 0; s >>= 1) {
        if (tid < s) red[tid] += red[tid + s];
        __syncthreads();
    }
    if (tid == 0) part[bid] = red[0];
}

// ---------- Kernel 2: LSTM scan, 4 single-wave blocks ----------
// Lane l owns gate rows l and l+64 (l<32: i,g ; l>=32: f,o). h register-
// resident; broadcast via v_readlane; i/f<->g/o via permlane32_swap.
// Weights as 64 NAMED scalars; z accumulation split 4-way for ILP.
#define RL(v, k) __builtin_bit_cast(float, \
    __builtin_amdgcn_readlane(__builtin_bit_cast(int, (v)), (k)))
#define DW(k) const float w0_##k = W_hh[r0 * 32 + (k)]; \
              const float w1_##k = W_hh[r1 * 32 + (k)];
#define GK(k, A0, A1) { const float hk = RL(h, k); \
                A0 = fmaf(hk, w0_##k, A0); A1 = fmaf(hk, w1_##k, A1); }

__global__ __launch_bounds__(64, 1) void lstm_kernel(
    const float* __restrict__ part,
    const float* __restrict__ W_ih, const float* __restrict__ W_hh,
    const float* __restrict__ b_ih, const float* __restrict__ b_hh,
    const float* __restrict__ gate_w, const float* __restrict__ gate_b,
    float* __restrict__ gates)
{
    __shared__ float cs[256];
    __shared__ float hist[257 * 33];     // stride-33: conflict-free epilogue reads

    const int b = blockIdx.x;            // batch 0..3
    const int l = threadIdx.x;           // lane 0..63
    const int r0 = l, r1 = l + 64;

    const float wih0 = W_ih[r0];
    const float wih1 = W_ih[r1];
    const float bias0 = b_ih[r0] + b_hh[r0];
    const float bias1 = b_ih[r1] + b_hh[r1];
    DW(0)  DW(1)  DW(2)  DW(3)  DW(4)  DW(5)  DW(6)  DW(7)
    DW(8)  DW(9)  DW(10) DW(11) DW(12) DW(13) DW(14) DW(15)
    DW(16) DW(17) DW(18) DW(19) DW(20) DW(21) DW(22) DW(23)
    DW(24) DW(25) DW(26) DW(27) DW(28) DW(29) DW(30) DW(31)

    // combine half-channel partials -> channel means for this batch
    const f32x2* __restrict__ p2 = (const f32x2*)part + b * 256;
#pragma unroll
    for (int j = 0; j < 4; j++) {
        const int cch = j * 64 + l;
        f32x2 pr = p2[cch];
        cs[cch] = (pr.x + pr.y) * MEAN_DEN;
    }

    float h = 0.0f, cstate = 0.0f;
    for (int t = 0; t < 256; t++) {
        const float inp = cs[t];
        float a0 = fmaf(inp, wih0, bias0), b0 = 0.f, c0 = 0.f, d0 = 0.f;
        float a1 = fmaf(inp, wih1, bias1), b1 = 0.f, c1 = 0.f, d1 = 0.f;
        GK(0,a0,a1)  GK(1,b0,b1)  GK(2,c0,c1)  GK(3,d0,d1)
        GK(4,a0,a1)  GK(5,b0,b1)  GK(6,c0,c1)  GK(7,d0,d1)
        GK(8,a0,a1)  GK(9,b0,b1)  GK(10,c0,c1) GK(11,d0,d1)
        GK(12,a0,a1) GK(13,b0,b1) GK(14,c0,c1) GK(15,d0,d1)
        GK(16,a0,a1) GK(17,b0,b1) GK(18,c0,c1) GK(19,d0,d1)
        GK(20,a0,a1) GK(21,b0,b1) GK(22,c0,c1) GK(23,d0,d1)
        GK(24,a0,a1) GK(25,b0,b1) GK(26,c0,c1) GK(27,d0,d1)
        GK(28,a0,a1) GK(29,b0,b1) GK(30,c0,c1) GK(31,d0,d1)
        const float z0 = (a0 + b0) + (c0 + d0);
        const float z1 = (a1 + b1) + (c1 + d1);
        float zf, zo;
#if __has_builtin(__builtin_amdgcn_permlane32_swap)
        {
            auto ra = __builtin_amdgcn_permlane32_swap(
                __builtin_bit_cast(uint, z0), __builtin_bit_cast(uint, z0), false, false);
            auto rb = __builtin_amdgcn_permlane32_swap(
                __builtin_bit_cast(uint, z1), __builtin_bit_cast(uint, z1), false, false);
            zf = __builtin_bit_cast(float, ra[1]);
            zo = __builtin_bit_cast(float, rb[1]);
        }
#else
        zf = __shfl_xor(z0, 32);
        zo = __shfl_xor(z1, 32);
#endif
        // valid in lanes<32 only (high lanes compute finite garbage, never read)
        cstate = sigf(zf) * cstate + sigf(z0) * tanh_fast(z1);
        h = sigf(zo) * tanh_fast(cstate);
        if (l < 32) hist[(t + 1) * 33 + l] = h;   // off critical path
    }

    // deferred output gates: lane handles t = l, l+64, l+128, l+192
    const float gb = gate_b[0];
#pragma unroll
    for (int chunk = 0; chunk < 4; chunk++) {
        const int t = chunk * 64 + l;
        const float* hrow = &hist[(t + 1) * 33];
        float s = gb;
#pragma unroll
        for (int k = 0; k < 32; k++) s = fmaf(hrow[k], gate_w[k], s);
        gates[b * 256 + t] = sigf(s);
    }
}

// ---------- Kernel 3: out = x * gate[ch], NORMAL stores ----------
// 2048 blocks, 8 loads + 8 stores per scheduling window. Normal (cached)
// stores: R9 measured 151us/rep @5.33TB/s with half the reads L3-absorbed;
// NT stores bypass L3 and were ~90us slower.
__global__ __launch_bounds__(256) void scale_kernel(const float* __restrict__ x,
                                                    const float* __restrict__ gates,
                                                    float* __restrict__ out) {
    const int bid = blockIdx.x;
    const int ch = bid >> 1, half = bid & 1;
    const float g = gates[ch];
    const size_t off = (size_t)ch * 32768 + half * 16384;
    const f32x4* __restrict__ xi = (const f32x4*)x + off;
    f32x4* __restrict__ oi = (f32x4*)out + off;
    const int tid = threadIdx.x;
#pragma unroll
    for (int gr = 0; gr < 8; gr++) {
        f32x4 v[8];
#pragma unroll
        for (int u = 0; u < 8; u++) v[u] = xi[gr * 2048 + u * 256 + tid];
#pragma unroll
        for (int u = 0; u < 8; u++) {
            v[u] *= g;
            oi[gr * 2048 + u * 256 + tid] = v[u];
        }
    }
}

extern "C" void kernel_launch(void* const* d_in, const int* in_sizes, int n_in,
                              void* d_out, int out_size, void* d_ws, size_t ws_size,
                              hipStream_t stream) {
    const float* x      = (const float*)d_in[0];
    const float* W_ih   = (const float*)d_in[1];   // (128,1)
    const float* W_hh   = (const float*)d_in[2];   // (128,32)
    const float* b_ih   = (const float*)d_in[3];   // (128,)
    const float* b_hh   = (const float*)d_in[4];   // (128,)
    const float* gate_w = (const float*)d_in[5];   // (1,32)
    const float* gate_b = (const float*)d_in[6];   // (1,)
    float* out = (float*)d_out;

    float* part  = (float*)d_ws;          // 2048 floats: half-channel partials
    float* gates = (float*)d_ws + 2048;   // 1024 floats

    mean_kernel<<<2048, 256, 0, stream>>>(x, part);
    lstm_kernel<<<4, 64, 0, stream>>>(part, W_ih, W_hh, b_ih, b_hh,
                                      gate_w, gate_b, gates);
    scale_kernel<<<2048, 256, 0, stream>>>(x, gates, out);
}